// Round 12
// baseline (220.238 us; speedup 1.0000x reference)
//
#include <hip/hip_runtime.h>
#include <cstddef>

#define TT 2048
#define BB 64
#define DD 256
#define LN_EPS 1e-5f
#define WEPS 1e-4f

typedef __attribute__((ext_vector_type(8))) short short8;
typedef __attribute__((ext_vector_type(4))) float f32x4;
typedef __attribute__((ext_vector_type(8))) _Float16 f16x8;
typedef __attribute__((ext_vector_type(4))) _Float16 f16x4;

__device__ __forceinline__ unsigned short f2h(float f) {
  _Float16 h = (_Float16)f;
  return *(unsigned short*)&h;
}
__device__ __forceinline__ float h2f(unsigned short u) {
  _Float16 h = *(_Float16*)&u;
  return (float)h;
}
// async global->LDS, 16B/lane; dest wave-uniform base (+lane*16 by HW)
__device__ __forceinline__ void gload16(unsigned short* lds, const unsigned short* g) {
  __builtin_amdgcn_global_load_lds(
      (const __attribute__((address_space(1))) void*)g,
      (__attribute__((address_space(3))) void*)lds, 16, 0, 0);
}

// ---- K1: fused LN stats + column partial sums (single x pass) ----
__global__ __launch_bounds__(256) void prepass_kernel(const float* __restrict__ x,
    float* __restrict__ stats, float* __restrict__ part) {
  int c = blockIdx.x;
  int b = blockIdx.y;
  int tid = threadIdx.x;
  int wave = tid >> 6, lane = tid & 63;
  int rowbase = b * TT + c * 128 + wave * 32;
  const float* xb = x + (size_t)rowbase * DD + lane * 4;
  float a0 = 0.f, a1 = 0.f, a2 = 0.f, a3 = 0.f;
  for (int i = 0; i < 32; ++i) {
    float4 v = *(const float4*)&xb[(size_t)i * DD];
    float s  = v.x + v.y + v.z + v.w;
    float sq = v.x*v.x + v.y*v.y + v.z*v.z + v.w*v.w;
    #pragma unroll
    for (int off = 32; off; off >>= 1) { s += __shfl_xor(s, off); sq += __shfl_xor(sq, off); }
    float mean = s * (1.f/DD);
    float var  = fmaxf(sq * (1.f/DD) - mean*mean, 0.f);
    float rstd = rsqrtf(var + LN_EPS);
    if (lane == 0) {
      stats[2*(rowbase+i)]   = mean;
      stats[2*(rowbase+i)+1] = rstd;
    }
    a0 += (v.x - mean) * rstd;
    a1 += (v.y - mean) * rstd;
    a2 += (v.z - mean) * rstd;
    a3 += (v.w - mean) * rstd;
  }
  int pidx = c * 4 + wave;
  *(float4*)&part[((size_t)pidx*BB + b)*DD + lane*4] = make_float4(a0, a1, a2, a3);
}

__global__ __launch_bounds__(256) void mu_finalize_kernel(const float* __restrict__ part,
                                                          const float* __restrict__ gamma,
                                                          const float* __restrict__ beta,
                                                          float* __restrict__ mu) {
  int b = blockIdx.x;
  int d = threadIdx.x;
  float s = 0.f;
  #pragma unroll 8
  for (int c = 0; c < 64; ++c) s += part[((size_t)c*BB + b)*DD + d];
  mu[b*DD + d] = gamma[d] * s * (1.f/TT) + beta[d];
}

// ---- K3: cov via fp16 MFMA, K-loop double-buffered (T3-min) ----
__global__ __launch_bounds__(256) void cov_mfma(const float* __restrict__ x,
    const float* __restrict__ stats, const float* __restrict__ gamma,
    const float* __restrict__ beta, const float* __restrict__ mu,
    unsigned short* __restrict__ Ch) {
  int flat = blockIdx.y * gridDim.x + blockIdx.x;  // [0,640); XCD-bijective remap
  int kx = flat & 7, j = flat >> 3;
  int b = (kx << 3) + j / 10;
  int tile = j - (j / 10) * 10;
  int p = 0, t = tile;
  while (t >= 4 - p) { t -= (4 - p); ++p; }
  int q = p + t;
  int i0 = p * 64, j0 = q * 64;
  bool diag = (p == q);

  __shared__ unsigned short sm[16384];   // 2 x (sA 4096 + sB 4096) shorts = 32KB
  __shared__ float sGi[64], sBi[64], sGj[64], sBj[64];

  int tid = threadIdx.x;
  const float* mub = mu + (size_t)b*DD;
  if (tid < 64) {
    sGi[tid] = gamma[i0+tid]; sBi[tid] = beta[i0+tid] - mub[i0+tid];
    sGj[tid] = gamma[j0+tid]; sBj[tid] = beta[j0+tid] - mub[j0+tid];
  }
  __syncthreads();

  int wave = tid >> 6, lane = tid & 63;
  int lr = lane & 15, lg = lane >> 4;
  int tg4 = tid >> 4;
  int dg  = tid & 15;
  int d0 = dg * 4;
  const float* xb  = x + (size_t)b*TT*DD;
  const float* stb = stats + (size_t)b*TT*2;

  float4 gi4 = *(const float4*)&sGi[d0];
  float4 bi4 = *(const float4*)&sBi[d0];
  float4 gj4 = *(const float4*)&sGj[d0];
  float4 bj4 = *(const float4*)&sBj[d0];

  int ch16 = tg4 >> 1, half = tg4 & 1;
  int widx[4];
  #pragma unroll
  for (int jj = 0; jj < 4; ++jj) {
    int dl = d0 + jj;
    int swz = (ch16 ^ (dl & 7) ^ ((dl >> 3) & 7)) & 7;
    widx[jj] = dl*64 + swz*8 + half*4;
  }

  f32x4 acc[4] = {};

  // staging body: transform x rows [k0, k0+64) into buffer at dst (sA) / dst+4096 (sB)
  #define COV_STAGE(k0v, dst)                                                  \
  {                                                                            \
    int trow = (k0v) + tg4 * 4;                                                \
    float4 s01 = *(const float4*)&stb[2*trow];                                 \
    float4 s23 = *(const float4*)&stb[2*trow + 4];                             \
    float mm[4] = {s01.x, s01.z, s23.x, s23.z};                                \
    float rr[4] = {s01.y, s01.w, s23.y, s23.w};                                \
    {                                                                          \
      _Float16 va[4][4];                                                       \
      _Pragma("unroll")                                                        \
      for (int i = 0; i < 4; ++i) {                                            \
        float4 v = *(const float4*)&xb[(size_t)(trow+i)*DD + i0 + d0];         \
        va[i][0] = (_Float16)(((v.x - mm[i]) * rr[i]) * gi4.x + bi4.x);        \
        va[i][1] = (_Float16)(((v.y - mm[i]) * rr[i]) * gi4.y + bi4.y);        \
        va[i][2] = (_Float16)(((v.z - mm[i]) * rr[i]) * gi4.z + bi4.z);        \
        va[i][3] = (_Float16)(((v.w - mm[i]) * rr[i]) * gi4.w + bi4.w);        \
      }                                                                        \
      _Pragma("unroll")                                                        \
      for (int jj = 0; jj < 4; ++jj) {                                         \
        f16x4 w = {va[0][jj], va[1][jj], va[2][jj], va[3][jj]};                \
        *(f16x4*)&(dst)[widx[jj]] = w;                                         \
      }                                                                        \
    }                                                                          \
    if (!diag) {                                                               \
      _Float16 vb[4][4];                                                       \
      _Pragma("unroll")                                                        \
      for (int i = 0; i < 4; ++i) {                                            \
        float4 v = *(const float4*)&xb[(size_t)(trow+i)*DD + j0 + d0];         \
        vb[i][0] = (_Float16)(((v.x - mm[i]) * rr[i]) * gj4.x + bj4.x);        \
        vb[i][1] = (_Float16)(((v.y - mm[i]) * rr[i]) * gj4.y + bj4.y);        \
        vb[i][2] = (_Float16)(((v.z - mm[i]) * rr[i]) * gj4.z + bj4.z);        \
        vb[i][3] = (_Float16)(((v.w - mm[i]) * rr[i]) * gj4.w + bj4.w);        \
      }                                                                        \
      _Pragma("unroll")                                                        \
      for (int jj = 0; jj < 4; ++jj) {                                         \
        f16x4 w = {vb[0][jj], vb[1][jj], vb[2][jj], vb[3][jj]};                \
        *(f16x4*)&(dst)[4096 + widx[jj]] = w;                                  \
      }                                                                        \
    }                                                                          \
  }

  COV_STAGE(0, sm);
  __syncthreads();

  for (int kk = 0; kk < 32; ++kk) {
    unsigned short* cur = sm + (kk & 1) * 8192;
    if (kk < 31) {
      unsigned short* nxt = sm + ((kk & 1) ^ 1) * 8192;
      COV_STAGE((kk + 1) * 64, nxt);
    }
    const unsigned short* pA = cur;
    const unsigned short* pB = diag ? cur : (cur + 4096);
    #pragma unroll
    for (int ks = 0; ks < 2; ++ks) {
      int rowA = wave*16 + lr;
      int cc = ks*4 + lg;
      int aoff = rowA*64 + (((cc ^ (rowA&7) ^ ((rowA>>3)&7)) & 7) << 3);
      f16x8 av = *(const f16x8*)&pA[aoff];
      #pragma unroll
      for (int n = 0; n < 4; ++n) {
        int rowB = n*16 + lr;
        int boff = rowB*64 + (((cc ^ (rowB&7) ^ ((rowB>>3)&7)) & 7) << 3);
        f16x8 bv = *(const f16x8*)&pB[boff];
        acc[n] = __builtin_amdgcn_mfma_f32_16x16x32_f16(av, bv, acc[n], 0, 0, 0);
      }
    }
    __syncthreads();
  }
  #undef COV_STAGE

  float* sC = (float*)sm;
  #pragma unroll
  for (int n = 0; n < 4; ++n)
    #pragma unroll
    for (int r = 0; r < 4; ++r)
      sC[(wave*16 + lg*4 + r)*65 + n*16 + lr] = acc[n][r];
  __syncthreads();
  unsigned short* Chb = Ch + (size_t)b*DD*DD;
  const float invTm1 = 1.f / (float)(TT - 1);
  int row = tid >> 2, cb = (tid & 3) * 16;
  int gi = i0 + row;
  unsigned short hv[16];
  #pragma unroll
  for (int e = 0; e < 16; ++e) {
    float v = sC[row*65 + cb + e] * invTm1;
    int gj = j0 + cb + e;
    if (gi == gj) v += WEPS;
    hv[e] = f2h(v);
    if (!diag) Chb[(size_t)gj*DD + gi] = hv[e];
  }
  size_t go = (size_t)gi*DD + j0 + cb;
  *(short8*)&Chb[go]     = *(short8*)&hv[0];
  *(short8*)&Chb[go + 8] = *(short8*)&hv[8];
}

// ---- K3b: power iteration in LDS (fp16 C); s = 1.05 * ||C v|| ----
__global__ __launch_bounds__(256) void power_kernel(
    const unsigned short* __restrict__ Ch, float* __restrict__ sbuf) {
  int b = blockIdx.x, tid = threadIdx.x;
  __shared__ unsigned short sC[DD*DD];   // 128 KB
  __shared__ float v[DD];
  __shared__ float red[4];
  const unsigned short* Cb = Ch + (size_t)b*DD*DD;
  #pragma unroll
  for (int i = 0; i < 32; ++i) {
    int chunkid = i*256 + tid;
    int r = chunkid >> 5, ch = chunkid & 31;
    short8 qv = *(const short8*)&Cb[(size_t)chunkid*8];
    *(short8*)&sC[r*256 + ((ch ^ (r & 7)) << 3)] = qv;
  }
  unsigned u = (unsigned)tid * 2654435761u;
  v[tid] = 0.5f + (float)((u >> 9) & 1023) * (1.f/1024.f);
  __syncthreads();
  float lam = 1.f;
  for (int it = 0; it < 10; ++it) {
    float w = 0.f;
    #pragma unroll
    for (int ch = 0; ch < 32; ++ch) {
      short8 hq = *(const short8*)&sC[tid*256 + ((ch ^ (tid & 7)) << 3)];
      const float* vp = &v[ch*8];
      #pragma unroll
      for (int e = 0; e < 8; ++e) w += h2f((unsigned short)hq[e]) * vp[e];
    }
    float ssq = w * w;
    #pragma unroll
    for (int off = 32; off; off >>= 1) ssq += __shfl_xor(ssq, off);
    if ((tid & 63) == 0) red[tid >> 6] = ssq;
    __syncthreads();
    float nrm = sqrtf(red[0] + red[1] + red[2] + red[3]);
    lam = nrm;
    v[tid] = w / nrm;
    __syncthreads();
  }
  if (tid == 0) sbuf[b] = lam * 1.05f;
}

// ---- 128x128-tile fp16 MFMA GEMM body, dbuf K-pipeline (T3-min) ----
__device__ __forceinline__ void bgemm_tile2(
    const unsigned short* __restrict__ A, const unsigned short* __restrict__ B,
    unsigned short* __restrict__ C,
    float alpha, float diagBeta, int tilex, int b, unsigned short* sm) {
  const int tid = threadIdx.x;
  const int i0g = (tilex >> 1) * 128, j0g = (tilex & 1) * 128;
  const size_t mb = (size_t)b * DD * DD;
  const int wave = tid >> 6, lane = tid & 63;
  const int wr = wave >> 2, wc = wave & 3;
  const int lr = lane & 15, lg = lane >> 4;

  f32x4 acc[8] = {};

  // prologue: stage k0=0 into sel 0 (sA at sm, sB at sm+8192)
  #pragma unroll
  for (int p2 = 0; p2 < 2; ++p2) {
    int slot = tid + p2 * 512;
    int row = slot >> 3, c = slot & 7;
    int srcc = (c ^ (row & 7)) << 3;
    int base = (wave * 64 + p2 * 512) * 8;
    gload16(&sm[base], A + mb + (size_t)(i0g + row) * DD + srcc);
    gload16(&sm[8192 + base], B + mb + (size_t)(j0g + row) * DD + srcc);
  }
  __syncthreads();

  #pragma unroll
  for (int kk = 0; kk < 4; ++kk) {
    unsigned short* cur = sm + (kk & 1) * 16384;
    if (kk < 3) {
      unsigned short* nxt = sm + ((kk & 1) ^ 1) * 16384;
      int k0n = (kk + 1) * 64;
      #pragma unroll
      for (int p2 = 0; p2 < 2; ++p2) {
        int slot = tid + p2 * 512;
        int row = slot >> 3, c = slot & 7;
        int srcc = (c ^ (row & 7)) << 3;
        int base = (wave * 64 + p2 * 512) * 8;
        gload16(&nxt[base], A + mb + (size_t)(i0g + row) * DD + k0n + srcc);
        gload16(&nxt[8192 + base], B + mb + (size_t)(j0g + row) * DD + k0n + srcc);
      }
    }
    #pragma unroll
    for (int ks = 0; ks < 2; ++ks) {
      int cc = ks * 4 + lg;
      f16x8 bv[2];
      #pragma unroll
      for (int n = 0; n < 2; ++n) {
        int rowB = wc * 32 + n * 16 + lr;
        int boff = rowB * 64 + ((cc ^ (rowB & 7)) * 8);
        bv[n] = *(const f16x8*)&cur[8192 + boff];
      }
      #pragma unroll
      for (int m = 0; m < 4; ++m) {
        int rowA = wr * 64 + m * 16 + lr;
        int aoff = rowA * 64 + ((cc ^ (rowA & 7)) * 8);
        f16x8 av = *(const f16x8*)&cur[aoff];
        #pragma unroll
        for (int n = 0; n < 2; ++n)
          acc[m*2+n] = __builtin_amdgcn_mfma_f32_16x16x32_f16(av, bv[n], acc[m*2+n], 0, 0, 0);
      }
    }
    __syncthreads();
  }

  #pragma unroll
  for (int m = 0; m < 4; ++m) {
    #pragma unroll
    for (int n = 0; n < 2; ++n) {
      int col = j0g + wc * 32 + n * 16 + lr;
      int row0 = i0g + wr * 64 + m * 16 + lg * 4;
      #pragma unroll
      for (int r = 0; r < 4; ++r) {
        float vv = alpha * acc[m*2+n][r];
        int row = row0 + r;
        if (row == col) vv += diagBeta;
        C[mb + (size_t)row * DD + col] = f2h(vv);
      }
    }
  }
}

__global__ __launch_bounds__(512) void bgemm_mfma2(
    const unsigned short* __restrict__ A, const unsigned short* __restrict__ B,
    unsigned short* __restrict__ C, float alpha, float diagBeta) {
  __shared__ unsigned short sm[32768];
  int flat = blockIdx.y * gridDim.x + blockIdx.x;
  int kx = flat & 7, j = flat >> 3;
  int b = (kx << 3) + (j >> 2);
  int tile = j & 3;
  bgemm_tile2(A, B, C, alpha, diagBeta, tile, b, sm);
}

__global__ __launch_bounds__(512) void bgemm_dual2(
    const unsigned short* __restrict__ A0, const unsigned short* __restrict__ B0,
    unsigned short* __restrict__ C0,
    const unsigned short* __restrict__ A1, const unsigned short* __restrict__ B1,
    unsigned short* __restrict__ C1) {
  __shared__ unsigned short sm[32768];
  int flat = blockIdx.y * gridDim.x + blockIdx.x;
  int kx = flat & 7, j = flat >> 3;
  int b = (kx << 3) + (j >> 3);
  int t8 = j & 7;
  int half = t8 >> 2, tile = t8 & 3;
  if (half == 0)
    bgemm_tile2(A0, B0, C0, 0.5f, 0.f, tile, b, sm);
  else
    bgemm_tile2(A1, B1, C1, 0.5f, 0.f, tile, b, sm);
}

// ---- P0: fused first NS iteration from C alone (dbuf body):
//   Y1 = (1.5/s) C - (0.5/s^2) C*C ; Z1 = 1.5 I - (0.5/s) C
__global__ __launch_bounds__(512) void bgemm_p0(
    const unsigned short* __restrict__ C, unsigned short* __restrict__ Y1,
    unsigned short* __restrict__ Z1, const float* __restrict__ sbuf) {
  __shared__ unsigned short sm[32768];
  int flat = blockIdx.y * gridDim.x + blockIdx.x;
  int kx = flat & 7, j = flat >> 3;
  int b = (kx << 3) + (j >> 2);
  int tilex = j & 3;

  const int tid = threadIdx.x;
  const int i0g = (tilex >> 1) * 128, j0g = (tilex & 1) * 128;
  const size_t mb = (size_t)b * DD * DD;
  const int wave = tid >> 6, lane = tid & 63;
  const int wr = wave >> 2, wc = wave & 3;
  const int lr = lane & 15, lg = lane >> 4;

  f32x4 acc[8] = {};

  #pragma unroll
  for (int p2 = 0; p2 < 2; ++p2) {
    int slot = tid + p2 * 512;
    int row = slot >> 3, c = slot & 7;
    int srcc = (c ^ (row & 7)) << 3;
    int base = (wave * 64 + p2 * 512) * 8;
    gload16(&sm[base], C + mb + (size_t)(i0g + row) * DD + srcc);
    gload16(&sm[8192 + base], C + mb + (size_t)(j0g + row) * DD + srcc);
  }
  __syncthreads();

  #pragma unroll
  for (int kk = 0; kk < 4; ++kk) {
    unsigned short* cur = sm + (kk & 1) * 16384;
    if (kk < 3) {
      unsigned short* nxt = sm + ((kk & 1) ^ 1) * 16384;
      int k0n = (kk + 1) * 64;
      #pragma unroll
      for (int p2 = 0; p2 < 2; ++p2) {
        int slot = tid + p2 * 512;
        int row = slot >> 3, c = slot & 7;
        int srcc = (c ^ (row & 7)) << 3;
        int base = (wave * 64 + p2 * 512) * 8;
        gload16(&nxt[base], C + mb + (size_t)(i0g + row) * DD + k0n + srcc);
        gload16(&nxt[8192 + base], C + mb + (size_t)(j0g + row) * DD + k0n + srcc);
      }
    }
    #pragma unroll
    for (int ks = 0; ks < 2; ++ks) {
      int cc = ks * 4 + lg;
      f16x8 bv[2];
      #pragma unroll
      for (int n = 0; n < 2; ++n) {
        int rowB = wc * 32 + n * 16 + lr;
        int boff = rowB * 64 + ((cc ^ (rowB & 7)) * 8);
        bv[n] = *(const f16x8*)&cur[8192 + boff];
      }
      #pragma unroll
      for (int m = 0; m < 4; ++m) {
        int rowA = wr * 64 + m * 16 + lr;
        int aoff = rowA * 64 + ((cc ^ (rowA & 7)) * 8);
        f16x8 av = *(const f16x8*)&cur[aoff];
        #pragma unroll
        for (int n = 0; n < 2; ++n)
          acc[m*2+n] = __builtin_amdgcn_mfma_f32_16x16x32_f16(av, bv[n], acc[m*2+n], 0, 0, 0);
      }
    }
    __syncthreads();
  }

  float invs = 1.f / sbuf[b];
  float a2 = -0.5f * invs * invs;
  float a1c = 1.5f * invs;
  float z1c = -0.5f * invs;
  #pragma unroll
  for (int m = 0; m < 4; ++m) {
    #pragma unroll
    for (int n = 0; n < 2; ++n) {
      int col = j0g + wc * 32 + n * 16 + lr;
      int row0 = i0g + wr * 64 + m * 16 + lg * 4;
      #pragma unroll
      for (int r = 0; r < 4; ++r) {
        int row = row0 + r;
        float cv = h2f(C[mb + (size_t)row * DD + col]);
        float yv = a2 * acc[m*2+n][r] + a1c * cv;
        float zv = z1c * cv + ((row == col) ? 1.5f : 0.f);
        Y1[mb + (size_t)row * DD + col] = f2h(yv);
        Z1[mb + (size_t)row * DD + col] = f2h(zv);
      }
    }
  }
}

// ---- K6: out = Xc @ (Z / sqrt(s)); 128x128 tile, 512 thr, dbuf K-pipeline ----
__global__ __launch_bounds__(512) void out_mfma2(const float* __restrict__ x,
    const float* __restrict__ stats, const float* __restrict__ gamma,
    const float* __restrict__ beta, const float* __restrict__ mu,
    const unsigned short* __restrict__ Z, const float* __restrict__ sbuf,
    float* __restrict__ out) {
  int flat = blockIdx.y * gridDim.x + blockIdx.x;  // [0,2048)
  int kx = flat & 7, j = flat >> 3;                // j in [0,256)
  int b = (kx << 3) + (j >> 5);
  int tile = j & 31;                               // 16 t-tiles x 2 f-tiles
  int t0 = (tile >> 1) * 128, f0 = (tile & 1) * 128;
  __shared__ unsigned short sm[32768];             // 2 x (sA 8192 + sB 8192)
  __shared__ float sG[256], sBs[256];

  int tid = threadIdx.x;
  if (tid < 256) {
    sG[tid] = gamma[tid];
    sBs[tid] = beta[tid] - mu[(size_t)b*DD + tid];
  }
  __syncthreads();

  const int wave = tid >> 6, lane = tid & 63;
  const int wr = wave >> 2, wc = wave & 3;
  const int lr = lane & 15, lg = lane >> 4;
  const float* xb  = x + (size_t)b*TT*DD;
  const float* stb = stats + (size_t)b*TT*2;
  const unsigned short* Zb = Z + (size_t)b*DD*DD;

  f32x4 acc[8] = {};

  // stage body: k0 into buffer dst (sA at dst, sB at dst+8192)
  #define OUT_STAGE(k0v, dst)                                                  \
  {                                                                            \
    _Pragma("unroll")                                                          \
    for (int p2 = 0; p2 < 2; ++p2) {                                           \
      int slot = tid + p2 * 512;                                               \
      int row = slot >> 3, c0 = slot & 7;                                      \
      int srcc = (c0 ^ (row & 7)) << 3;                                        \
      size_t gz = (size_t)(f0 + row) * DD + (k0v) + srcc;                      \
      int base = (wave * 64 + p2 * 512) * 8;                                   \
      gload16(&(dst)[8192 + base], Zb + gz);                                   \
      int trow = t0 + row;                                                     \
      float mean = stb[2*trow], rstd = stb[2*trow+1];                          \
      const float* xr = xb + (size_t)trow*DD + (k0v) + c0*8;                   \
      _Float16 h8[8];                                                          \
      _Pragma("unroll")                                                        \
      for (int qq = 0; qq < 2; ++qq) {                                         \
        float4 v = *(const float4*)&xr[qq*4];                                  \
        float vvv[4] = {v.x, v.y, v.z, v.w};                                   \
        _Pragma("unroll")                                                      \
        for (int e2 = 0; e2 < 4; ++e2) {                                       \
          int d = (k0v) + c0*8 + qq*4 + e2;                                    \
          h8[qq*4+e2] = (_Float16)((vvv[e2] - mean) * rstd * sG[d] + sBs[d]);  \
        }                                                                      \
      }                                                                        \
      int ld = row * 64 + ((c0 ^ (row & 7)) * 8);                              \
      *(f16x8*)&(dst)[ld] = *(f16x8*)&h8[0];                                   \
    }                                                                          \
  }

  OUT_STAGE(0, sm);
  __syncthreads();

  #pragma unroll
  for (int kk = 0; kk < 4; ++kk) {
    unsigned short* cur = sm + (kk & 1) * 16384;
    if (kk < 3) {
      unsigned short* nxt = sm + ((kk & 1) ^ 1) * 16384;
      OUT_STAGE((kk + 1) * 64, nxt);
    }
    #pragma unroll
    for (int ks = 0; ks < 2; ++ks) {
      int cc = ks * 4 + lg;
      f16x8 bv[2];
      #pragma unroll
      for (int n = 0; n < 2; ++n) {
        int rowB = wc * 32 + n * 16 + lr;
        int boff = rowB * 64 + ((cc ^ (rowB & 7)) * 8);
        bv[n] = *(const f16x8*)&cur[8192 + boff];
      }
      #pragma unroll
      for (int m = 0; m < 4; ++m) {
        int rowA = wr * 64 + m * 16 + lr;
        int aoff = rowA * 64 + ((cc ^ (rowA & 7)) * 8);
        f16x8 av = *(const f16x8*)&cur[aoff];
        #pragma unroll
        for (int n = 0; n < 2; ++n)
          acc[m*2+n] = __builtin_amdgcn_mfma_f32_16x16x32_f16(av, bv[n], acc[m*2+n], 0, 0, 0);
      }
    }
    __syncthreads();
  }
  #undef OUT_STAGE

  float rs = rsqrtf(sbuf[b]);
  float* ob = out + (size_t)b*TT*DD;
  #pragma unroll
  for (int m = 0; m < 4; ++m) {
    #pragma unroll
    for (int n = 0; n < 2; ++n) {
      int col = f0 + wc * 32 + n * 16 + lr;
      int row0 = t0 + wr * 64 + m * 16 + lg * 4;
      #pragma unroll
      for (int r = 0; r < 4; ++r)
        ob[(size_t)(row0 + r)*DD + col] = acc[m*2+n][r] * rs;
    }
  }
}

extern "C" void kernel_launch(void* const* d_in, const int* in_sizes, int n_in,
                              void* d_out, int out_size, void* d_ws, size_t ws_size,
                              hipStream_t stream) {
  const float* x     = (const float*)d_in[0];
  const float* gamma = (const float*)d_in[1];
  const float* beta  = (const float*)d_in[2];
  float* out = (float*)d_out;

  float* wsf   = (float*)d_ws;
  float* stats = wsf;                      // 262144 floats (1 MB)
  float* mu    = wsf + 262144;             // 16384
  float* sbuf  = wsf + 278528;             // 64
  unsigned short* nsb = (unsigned short*)(wsf + 278784);
  const size_t MATU = (size_t)BB * DD * DD;      // 4194304 ushorts (8 MB) per plane
  unsigned short* H[5];
  for (int k = 0; k < 5; ++k) H[k] = nsb + (size_t)k * MATU;
  // part (4 MB) aliased onto H1 (first written in P0, after mu_finalize reads it)
  float* part = (float*)H[1];

  prepass_kernel<<<dim3(16, BB), 256, 0, stream>>>(x, stats, part);
  mu_finalize_kernel<<<BB, 256, 0, stream>>>(part, gamma, beta, mu);
  cov_mfma<<<dim3(10, BB), 256, 0, stream>>>(x, stats, gamma, beta, mu, H[0]);
  power_kernel<<<BB, 256, 0, stream>>>(H[0], sbuf);

  // P0 (it1, fused): Y1 -> H3 ; Z1 -> H1       [C = H0]
  bgemm_p0<<<dim3(4, BB), 512, 0, stream>>>(H[0], H[3], H[1], sbuf);
  // it2: M2 = 3I - Z1*Y1 -> H2 ; Y2 = 0.5 Y1*M2 -> H0 ; Z2 = 0.5 M2*Z1 -> H4
  bgemm_mfma2<<<dim3(4, BB), 512, 0, stream>>>(H[1], H[3], H[2], -1.f, 3.f);
  bgemm_dual2<<<dim3(8, BB), 512, 0, stream>>>(H[3], H[2], H[0], H[2], H[1], H[4]);
  // it3: M3 -> H2 ; Y3 = 0.5 Y2*M3 -> H3 ; Z3 = 0.5 M3*Z2 -> H1
  bgemm_mfma2<<<dim3(4, BB), 512, 0, stream>>>(H[4], H[0], H[2], -1.f, 3.f);
  bgemm_dual2<<<dim3(8, BB), 512, 0, stream>>>(H[0], H[2], H[3], H[2], H[4], H[1]);
  // it4 (Z-only): M4 -> H2 ; Z4 = 0.5 M4*Z3 -> H4
  bgemm_mfma2<<<dim3(4, BB), 512, 0, stream>>>(H[1], H[3], H[2], -1.f, 3.f);
  bgemm_mfma2<<<dim3(4, BB), 512, 0, stream>>>(H[2], H[1], H[4], 0.5f, 0.f);

  out_mfma2<<<dim3(32, BB), 512, 0, stream>>>(x, stats, gamma, beta, mu, H[4], sbuf, out);
}

// Round 13
// 199.780 us; speedup vs baseline: 1.1024x; 1.1024x over previous
//
#include <hip/hip_runtime.h>
#include <cstddef>

#define TT 2048
#define BB 64
#define DD 256
#define LN_EPS 1e-5f
#define WEPS 1e-4f

typedef __attribute__((ext_vector_type(8))) short short8;
typedef __attribute__((ext_vector_type(4))) float f32x4;
typedef __attribute__((ext_vector_type(8))) _Float16 f16x8;
typedef __attribute__((ext_vector_type(4))) _Float16 f16x4;

__device__ __forceinline__ unsigned short f2h(float f) {
  _Float16 h = (_Float16)f;
  return *(unsigned short*)&h;
}
__device__ __forceinline__ float h2f(unsigned short u) {
  _Float16 h = *(_Float16*)&u;
  return (float)h;
}
// async global->LDS, 16B/lane; dest wave-uniform base (+lane*16 by HW)
__device__ __forceinline__ void gload16(unsigned short* lds, const unsigned short* g) {
  __builtin_amdgcn_global_load_lds(
      (const __attribute__((address_space(1))) void*)g,
      (__attribute__((address_space(3))) void*)lds, 16, 0, 0);
}

// ---- K1: LN stats + write A = LN(x) fp16 (uncentered) + column partial sums ----
__global__ __launch_bounds__(256) void prepass_kernel(const float* __restrict__ x,
    const float* __restrict__ gamma, const float* __restrict__ beta,
    unsigned short* __restrict__ A, float* __restrict__ part) {
  int c = blockIdx.x;
  int b = blockIdx.y;
  int tid = threadIdx.x;
  int wave = tid >> 6, lane = tid & 63;
  int rowbase = b * TT + c * 128 + wave * 32;
  const float* xb = x + (size_t)rowbase * DD + lane * 4;
  unsigned short* Ab = A + (size_t)rowbase * DD + lane * 4;
  float4 g4 = *(const float4*)&gamma[lane * 4];
  float4 b4 = *(const float4*)&beta[lane * 4];
  float a0 = 0.f, a1 = 0.f, a2 = 0.f, a3 = 0.f;
  for (int i = 0; i < 32; ++i) {
    float4 v = *(const float4*)&xb[(size_t)i * DD];
    float s  = v.x + v.y + v.z + v.w;
    float sq = v.x*v.x + v.y*v.y + v.z*v.z + v.w*v.w;
    #pragma unroll
    for (int off = 32; off; off >>= 1) { s += __shfl_xor(s, off); sq += __shfl_xor(sq, off); }
    float mean = s * (1.f/DD);
    float var  = fmaxf(sq * (1.f/DD) - mean*mean, 0.f);
    float rstd = rsqrtf(var + LN_EPS);
    float c0 = (v.x - mean) * rstd, c1 = (v.y - mean) * rstd;
    float c2 = (v.z - mean) * rstd, c3 = (v.w - mean) * rstd;
    a0 += c0; a1 += c1; a2 += c2; a3 += c3;
    ushort4 w;
    w.x = f2h(c0 * g4.x + b4.x);
    w.y = f2h(c1 * g4.y + b4.y);
    w.z = f2h(c2 * g4.z + b4.z);
    w.w = f2h(c3 * g4.w + b4.w);
    *(ushort4*)&Ab[(size_t)i * DD] = w;
  }
  int pidx = c * 4 + wave;
  *(float4*)&part[((size_t)pidx*BB + b)*DD + lane*4] = make_float4(a0, a1, a2, a3);
}

// ---- K2: mu = gamma * colsum/T + beta  (mean of A columns) ----
__global__ __launch_bounds__(256) void mu_finalize_kernel(const float* __restrict__ part,
                                                          const float* __restrict__ gamma,
                                                          const float* __restrict__ beta,
                                                          float* __restrict__ mu) {
  int b = blockIdx.x;
  int d = threadIdx.x;
  float s = 0.f;
  #pragma unroll 8
  for (int c = 0; c < 64; ++c) s += part[((size_t)c*BB + b)*DD + d];
  mu[b*DD + d] = gamma[d] * s * (1.f/TT) + beta[d];
}

// ---- K3: cov = (Gram(A) - T mu mu^T)/(T-1) + eps I via fp16 MFMA, dbuf ----
__global__ __launch_bounds__(256) void cov_mfma(const unsigned short* __restrict__ A,
    const float* __restrict__ mu, unsigned short* __restrict__ Ch) {
  int flat = blockIdx.y * gridDim.x + blockIdx.x;  // [0,640); XCD-bijective remap
  int kx = flat & 7, j = flat >> 3;
  int b = (kx << 3) + j / 10;
  int tile = j - (j / 10) * 10;
  int p = 0, t = tile;
  while (t >= 4 - p) { t -= (4 - p); ++p; }
  int q = p + t;
  int i0 = p * 64, j0 = q * 64;
  bool diag = (p == q);

  __shared__ unsigned short sm[16384];   // 2 x (sA 4096 + sB 4096) ushorts = 32KB
  __shared__ float sMu[128];

  int tid = threadIdx.x;
  const float* mub = mu + (size_t)b*DD;
  if (tid < 64) { sMu[tid] = mub[i0+tid]; sMu[64+tid] = mub[j0+tid]; }
  __syncthreads();

  int wave = tid >> 6, lane = tid & 63;
  int lr = lane & 15, lg = lane >> 4;
  int tg4 = tid >> 4;
  int dg  = tid & 15;
  int d0 = dg * 4;
  const unsigned short* Ab = A + (size_t)b*TT*DD;

  int ch16 = tg4 >> 1, half = tg4 & 1;
  int widx[4];
  #pragma unroll
  for (int jj = 0; jj < 4; ++jj) {
    int dl = d0 + jj;
    int swz = (ch16 ^ (dl & 7) ^ ((dl >> 3) & 7)) & 7;
    widx[jj] = dl*64 + swz*8 + half*4;
  }

  f32x4 acc[4] = {};

  // stage A-slices [k0..k0+64) x 64d transposed into dst (sA) / dst+4096 (sB)
  #define COV_STAGE(k0v, dst)                                                  \
  {                                                                            \
    int trow = (k0v) + tg4 * 4;                                                \
    ushort4 sv0 = *(const ushort4*)&Ab[(size_t)(trow+0)*DD + i0 + d0];         \
    ushort4 sv1 = *(const ushort4*)&Ab[(size_t)(trow+1)*DD + i0 + d0];         \
    ushort4 sv2 = *(const ushort4*)&Ab[(size_t)(trow+2)*DD + i0 + d0];         \
    ushort4 sv3 = *(const ushort4*)&Ab[(size_t)(trow+3)*DD + i0 + d0];         \
    { ushort4 w = {sv0.x, sv1.x, sv2.x, sv3.x}; *(ushort4*)&(dst)[widx[0]] = w; } \
    { ushort4 w = {sv0.y, sv1.y, sv2.y, sv3.y}; *(ushort4*)&(dst)[widx[1]] = w; } \
    { ushort4 w = {sv0.z, sv1.z, sv2.z, sv3.z}; *(ushort4*)&(dst)[widx[2]] = w; } \
    { ushort4 w = {sv0.w, sv1.w, sv2.w, sv3.w}; *(ushort4*)&(dst)[widx[3]] = w; } \
    if (!diag) {                                                               \
      ushort4 t0v = *(const ushort4*)&Ab[(size_t)(trow+0)*DD + j0 + d0];       \
      ushort4 t1v = *(const ushort4*)&Ab[(size_t)(trow+1)*DD + j0 + d0];       \
      ushort4 t2v = *(const ushort4*)&Ab[(size_t)(trow+2)*DD + j0 + d0];       \
      ushort4 t3v = *(const ushort4*)&Ab[(size_t)(trow+3)*DD + j0 + d0];       \
      { ushort4 w = {t0v.x, t1v.x, t2v.x, t3v.x}; *(ushort4*)&(dst)[4096 + widx[0]] = w; } \
      { ushort4 w = {t0v.y, t1v.y, t2v.y, t3v.y}; *(ushort4*)&(dst)[4096 + widx[1]] = w; } \
      { ushort4 w = {t0v.z, t1v.z, t2v.z, t3v.z}; *(ushort4*)&(dst)[4096 + widx[2]] = w; } \
      { ushort4 w = {t0v.w, t1v.w, t2v.w, t3v.w}; *(ushort4*)&(dst)[4096 + widx[3]] = w; } \
    }                                                                          \
  }

  COV_STAGE(0, sm);
  __syncthreads();

  for (int kk = 0; kk < 32; ++kk) {
    unsigned short* cur = sm + (kk & 1) * 8192;
    if (kk < 31) {
      unsigned short* nxt = sm + ((kk & 1) ^ 1) * 8192;
      COV_STAGE((kk + 1) * 64, nxt);
    }
    const unsigned short* pA = cur;
    const unsigned short* pB = diag ? cur : (cur + 4096);
    #pragma unroll
    for (int ks = 0; ks < 2; ++ks) {
      int rowA = wave*16 + lr;
      int cc = ks*4 + lg;
      int aoff = rowA*64 + (((cc ^ (rowA&7) ^ ((rowA>>3)&7)) & 7) << 3);
      f16x8 av = *(const f16x8*)&pA[aoff];
      #pragma unroll
      for (int n = 0; n < 4; ++n) {
        int rowB = n*16 + lr;
        int boff = rowB*64 + (((cc ^ (rowB&7) ^ ((rowB>>3)&7)) & 7) << 3);
        f16x8 bv = *(const f16x8*)&pB[boff];
        acc[n] = __builtin_amdgcn_mfma_f32_16x16x32_f16(av, bv, acc[n], 0, 0, 0);
      }
    }
    __syncthreads();
  }
  #undef COV_STAGE

  float* sC = (float*)sm;
  #pragma unroll
  for (int n = 0; n < 4; ++n)
    #pragma unroll
    for (int r = 0; r < 4; ++r)
      sC[(wave*16 + lg*4 + r)*65 + n*16 + lr] = acc[n][r];
  __syncthreads();
  unsigned short* Chb = Ch + (size_t)b*DD*DD;
  const float invTm1 = 1.f / (float)(TT - 1);
  int row = tid >> 2, cb = (tid & 3) * 16;
  int gi = i0 + row;
  float mi = sMu[row] * (float)TT;
  unsigned short hv[16];
  #pragma unroll
  for (int e = 0; e < 16; ++e) {
    int gj = j0 + cb + e;
    float v = (sC[row*65 + cb + e] - mi * sMu[64 + cb + e]) * invTm1;
    if (gi == gj) v += WEPS;
    hv[e] = f2h(v);
    if (!diag) Chb[(size_t)gj*DD + gi] = hv[e];
  }
  size_t go = (size_t)gi*DD + j0 + cb;
  *(short8*)&Chb[go]     = *(short8*)&hv[0];
  *(short8*)&Chb[go + 8] = *(short8*)&hv[8];
}

// ---- K3b: power iteration in LDS (fp16 C); s = 1.05 * ||C v|| ----
__global__ __launch_bounds__(256) void power_kernel(
    const unsigned short* __restrict__ Ch, float* __restrict__ sbuf) {
  int b = blockIdx.x, tid = threadIdx.x;
  __shared__ unsigned short sC[DD*DD];   // 128 KB
  __shared__ float v[DD];
  __shared__ float red[4];
  const unsigned short* Cb = Ch + (size_t)b*DD*DD;
  #pragma unroll
  for (int i = 0; i < 32; ++i) {
    int chunkid = i*256 + tid;
    int r = chunkid >> 5, ch = chunkid & 31;
    short8 qv = *(const short8*)&Cb[(size_t)chunkid*8];
    *(short8*)&sC[r*256 + ((ch ^ (r & 7)) << 3)] = qv;
  }
  unsigned u = (unsigned)tid * 2654435761u;
  v[tid] = 0.5f + (float)((u >> 9) & 1023) * (1.f/1024.f);
  __syncthreads();
  float lam = 1.f;
  for (int it = 0; it < 10; ++it) {
    float w = 0.f;
    #pragma unroll
    for (int ch = 0; ch < 32; ++ch) {
      short8 hq = *(const short8*)&sC[tid*256 + ((ch ^ (tid & 7)) << 3)];
      const float* vp = &v[ch*8];
      #pragma unroll
      for (int e = 0; e < 8; ++e) w += h2f((unsigned short)hq[e]) * vp[e];
    }
    float ssq = w * w;
    #pragma unroll
    for (int off = 32; off; off >>= 1) ssq += __shfl_xor(ssq, off);
    if ((tid & 63) == 0) red[tid >> 6] = ssq;
    __syncthreads();
    float nrm = sqrtf(red[0] + red[1] + red[2] + red[3]);
    lam = nrm;
    v[tid] = w / nrm;
    __syncthreads();
  }
  if (tid == 0) sbuf[b] = lam * 1.05f;
}

// ---- 128x128-tile fp16 MFMA GEMM body, dbuf K-pipeline ----
__device__ __forceinline__ void bgemm_tile2(
    const unsigned short* __restrict__ A, const unsigned short* __restrict__ B,
    unsigned short* __restrict__ C,
    float alpha, float diagBeta, int tilex, int b, unsigned short* sm) {
  const int tid = threadIdx.x;
  const int i0g = (tilex >> 1) * 128, j0g = (tilex & 1) * 128;
  const size_t mb = (size_t)b * DD * DD;
  const int wave = tid >> 6, lane = tid & 63;
  const int wr = wave >> 2, wc = wave & 3;
  const int lr = lane & 15, lg = lane >> 4;

  f32x4 acc[8] = {};

  #pragma unroll
  for (int p2 = 0; p2 < 2; ++p2) {
    int slot = tid + p2 * 512;
    int row = slot >> 3, c = slot & 7;
    int srcc = (c ^ (row & 7)) << 3;
    int base = (wave * 64 + p2 * 512) * 8;
    gload16(&sm[base], A + mb + (size_t)(i0g + row) * DD + srcc);
    gload16(&sm[8192 + base], B + mb + (size_t)(j0g + row) * DD + srcc);
  }
  __syncthreads();

  #pragma unroll
  for (int kk = 0; kk < 4; ++kk) {
    unsigned short* cur = sm + (kk & 1) * 16384;
    if (kk < 3) {
      unsigned short* nxt = sm + ((kk & 1) ^ 1) * 16384;
      int k0n = (kk + 1) * 64;
      #pragma unroll
      for (int p2 = 0; p2 < 2; ++p2) {
        int slot = tid + p2 * 512;
        int row = slot >> 3, c = slot & 7;
        int srcc = (c ^ (row & 7)) << 3;
        int base = (wave * 64 + p2 * 512) * 8;
        gload16(&nxt[base], A + mb + (size_t)(i0g + row) * DD + k0n + srcc);
        gload16(&nxt[8192 + base], B + mb + (size_t)(j0g + row) * DD + k0n + srcc);
      }
    }
    #pragma unroll
    for (int ks = 0; ks < 2; ++ks) {
      int cc = ks * 4 + lg;
      f16x8 bv[2];
      #pragma unroll
      for (int n = 0; n < 2; ++n) {
        int rowB = wc * 32 + n * 16 + lr;
        int boff = rowB * 64 + ((cc ^ (rowB & 7)) * 8);
        bv[n] = *(const f16x8*)&cur[8192 + boff];
      }
      #pragma unroll
      for (int m = 0; m < 4; ++m) {
        int rowA = wr * 64 + m * 16 + lr;
        int aoff = rowA * 64 + ((cc ^ (rowA & 7)) * 8);
        f16x8 av = *(const f16x8*)&cur[aoff];
        #pragma unroll
        for (int n = 0; n < 2; ++n)
          acc[m*2+n] = __builtin_amdgcn_mfma_f32_16x16x32_f16(av, bv[n], acc[m*2+n], 0, 0, 0);
      }
    }
    __syncthreads();
  }

  #pragma unroll
  for (int m = 0; m < 4; ++m) {
    #pragma unroll
    for (int n = 0; n < 2; ++n) {
      int col = j0g + wc * 32 + n * 16 + lr;
      int row0 = i0g + wr * 64 + m * 16 + lg * 4;
      #pragma unroll
      for (int r = 0; r < 4; ++r) {
        float vv = alpha * acc[m*2+n][r];
        int row = row0 + r;
        if (row == col) vv += diagBeta;
        C[mb + (size_t)row * DD + col] = f2h(vv);
      }
    }
  }
}

__global__ __launch_bounds__(512) void bgemm_mfma2(
    const unsigned short* __restrict__ A, const unsigned short* __restrict__ B,
    unsigned short* __restrict__ C, float alpha, float diagBeta) {
  __shared__ unsigned short sm[32768];
  int flat = blockIdx.y * gridDim.x + blockIdx.x;
  int kx = flat & 7, j = flat >> 3;
  int b = (kx << 3) + (j >> 2);
  int tile = j & 3;
  bgemm_tile2(A, B, C, alpha, diagBeta, tile, b, sm);
}

__global__ __launch_bounds__(512) void bgemm_dual2(
    const unsigned short* __restrict__ A0, const unsigned short* __restrict__ B0,
    unsigned short* __restrict__ C0,
    const unsigned short* __restrict__ A1, const unsigned short* __restrict__ B1,
    unsigned short* __restrict__ C1) {
  __shared__ unsigned short sm[32768];
  int flat = blockIdx.y * gridDim.x + blockIdx.x;
  int kx = flat & 7, j = flat >> 3;
  int b = (kx << 3) + (j >> 3);
  int t8 = j & 7;
  int half = t8 >> 2, tile = t8 & 3;
  if (half == 0)
    bgemm_tile2(A0, B0, C0, 0.5f, 0.f, tile, b, sm);
  else
    bgemm_tile2(A1, B1, C1, 0.5f, 0.f, tile, b, sm);
}

// ---- P0: tuned stage-1 from C alone (a=1, b=2):
//   Y1 = 2 C~ - C~^2 ; Z1 = 2 I - C~    (C~ = C/s)
__global__ __launch_bounds__(512) void bgemm_p0(
    const unsigned short* __restrict__ C, unsigned short* __restrict__ Y1,
    unsigned short* __restrict__ Z1, const float* __restrict__ sbuf) {
  __shared__ unsigned short sm[32768];
  int flat = blockIdx.y * gridDim.x + blockIdx.x;
  int kx = flat & 7, j = flat >> 3;
  int b = (kx << 3) + (j >> 2);
  int tilex = j & 3;

  const int tid = threadIdx.x;
  const int i0g = (tilex >> 1) * 128, j0g = (tilex & 1) * 128;
  const size_t mb = (size_t)b * DD * DD;
  const int wave = tid >> 6, lane = tid & 63;
  const int wr = wave >> 2, wc = wave & 3;
  const int lr = lane & 15, lg = lane >> 4;

  f32x4 acc[8] = {};

  #pragma unroll
  for (int p2 = 0; p2 < 2; ++p2) {
    int slot = tid + p2 * 512;
    int row = slot >> 3, c = slot & 7;
    int srcc = (c ^ (row & 7)) << 3;
    int base = (wave * 64 + p2 * 512) * 8;
    gload16(&sm[base], C + mb + (size_t)(i0g + row) * DD + srcc);
    gload16(&sm[8192 + base], C + mb + (size_t)(j0g + row) * DD + srcc);
  }
  __syncthreads();

  #pragma unroll
  for (int kk = 0; kk < 4; ++kk) {
    unsigned short* cur = sm + (kk & 1) * 16384;
    if (kk < 3) {
      unsigned short* nxt = sm + ((kk & 1) ^ 1) * 16384;
      int k0n = (kk + 1) * 64;
      #pragma unroll
      for (int p2 = 0; p2 < 2; ++p2) {
        int slot = tid + p2 * 512;
        int row = slot >> 3, c = slot & 7;
        int srcc = (c ^ (row & 7)) << 3;
        int base = (wave * 64 + p2 * 512) * 8;
        gload16(&nxt[base], C + mb + (size_t)(i0g + row) * DD + k0n + srcc);
        gload16(&nxt[8192 + base], C + mb + (size_t)(j0g + row) * DD + k0n + srcc);
      }
    }
    #pragma unroll
    for (int ks = 0; ks < 2; ++ks) {
      int cc = ks * 4 + lg;
      f16x8 bv[2];
      #pragma unroll
      for (int n = 0; n < 2; ++n) {
        int rowB = wc * 32 + n * 16 + lr;
        int boff = rowB * 64 + ((cc ^ (rowB & 7)) * 8);
        bv[n] = *(const f16x8*)&cur[8192 + boff];
      }
      #pragma unroll
      for (int m = 0; m < 4; ++m) {
        int rowA = wr * 64 + m * 16 + lr;
        int aoff = rowA * 64 + ((cc ^ (rowA & 7)) * 8);
        f16x8 av = *(const f16x8*)&cur[aoff];
        #pragma unroll
        for (int n = 0; n < 2; ++n)
          acc[m*2+n] = __builtin_amdgcn_mfma_f32_16x16x32_f16(av, bv[n], acc[m*2+n], 0, 0, 0);
      }
    }
    __syncthreads();
  }

  float invs = 1.f / sbuf[b];
  float a2 = -invs * invs;       // coeff of C^2
  float a1c = 2.f * invs;        // coeff of C in Y1
  float z1c = -invs;             // coeff of C in Z1
  #pragma unroll
  for (int m = 0; m < 4; ++m) {
    #pragma unroll
    for (int n = 0; n < 2; ++n) {
      int col = j0g + wc * 32 + n * 16 + lr;
      int row0 = i0g + wr * 64 + m * 16 + lg * 4;
      #pragma unroll
      for (int r = 0; r < 4; ++r) {
        int row = row0 + r;
        float cv = h2f(C[mb + (size_t)row * DD + col]);
        float yv = a2 * acc[m*2+n][r] + a1c * cv;
        float zv = z1c * cv + ((row == col) ? 2.f : 0.f);
        Y1[mb + (size_t)row * DD + col] = f2h(yv);
        Z1[mb + (size_t)row * DD + col] = f2h(zv);
      }
    }
  }
}

// ---- rvec = mu^T W  (per batch) ----
__global__ __launch_bounds__(256) void matvec_r(const float* __restrict__ mu,
    const unsigned short* __restrict__ W, float* __restrict__ rvec) {
  int b = blockIdx.x, f = threadIdx.x;
  __shared__ float sMu[DD];
  sMu[f] = mu[(size_t)b*DD + f];
  __syncthreads();
  const unsigned short* Wb = W + (size_t)b*DD*DD;
  float acc = 0.f;
  #pragma unroll 8
  for (int d = 0; d < DD; ++d) acc += sMu[d] * h2f(Wb[(size_t)d*DD + f]);
  rvec[(size_t)b*DD + f] = acc;
}

// ---- K6: out = (A W - 1 rvec^T) / sqrt(s); pure dual-gload GEMM, dbuf ----
__global__ __launch_bounds__(512) void out_mfma2(const unsigned short* __restrict__ A,
    const unsigned short* __restrict__ W, const float* __restrict__ rvec,
    const float* __restrict__ sbuf, float* __restrict__ out) {
  int flat = blockIdx.y * gridDim.x + blockIdx.x;  // [0,2048)
  int kx = flat & 7, j = flat >> 3;                // j in [0,256)
  int b = (kx << 3) + (j >> 5);
  int tile = j & 31;                               // 16 t-tiles x 2 f-tiles
  int t0 = (tile >> 1) * 128, f0 = (tile & 1) * 128;
  __shared__ unsigned short sm[32768];             // dbuf 2 x (sA 8192 + sB 8192)

  int tid = threadIdx.x;
  const int wave = tid >> 6, lane = tid & 63;
  const int wr = wave >> 2, wc = wave & 3;
  const int lr = lane & 15, lg = lane >> 4;
  const unsigned short* Ab = A + (size_t)b*TT*DD;
  const unsigned short* Wb = W + (size_t)b*DD*DD;

  f32x4 acc[8] = {};

  #pragma unroll
  for (int p2 = 0; p2 < 2; ++p2) {
    int slot = tid + p2 * 512;
    int row = slot >> 3, c = slot & 7;
    int srcc = (c ^ (row & 7)) << 3;
    int base = (wave * 64 + p2 * 512) * 8;
    gload16(&sm[base], Ab + (size_t)(t0 + row) * DD + srcc);
    gload16(&sm[8192 + base], Wb + (size_t)(f0 + row) * DD + srcc);
  }
  __syncthreads();

  #pragma unroll
  for (int kk = 0; kk < 4; ++kk) {
    unsigned short* cur = sm + (kk & 1) * 16384;
    if (kk < 3) {
      unsigned short* nxt = sm + ((kk & 1) ^ 1) * 16384;
      int k0n = (kk + 1) * 64;
      #pragma unroll
      for (int p2 = 0; p2 < 2; ++p2) {
        int slot = tid + p2 * 512;
        int row = slot >> 3, c = slot & 7;
        int srcc = (c ^ (row & 7)) << 3;
        int base = (wave * 64 + p2 * 512) * 8;
        gload16(&nxt[base], Ab + (size_t)(t0 + row) * DD + k0n + srcc);
        gload16(&nxt[8192 + base], Wb + (size_t)(f0 + row) * DD + k0n + srcc);
      }
    }
    #pragma unroll
    for (int ks = 0; ks < 2; ++ks) {
      int cc = ks * 4 + lg;
      f16x8 bv[2];
      #pragma unroll
      for (int n = 0; n < 2; ++n) {
        int rowB = wc * 32 + n * 16 + lr;
        int boff = rowB * 64 + ((cc ^ (rowB & 7)) * 8);
        bv[n] = *(const f16x8*)&cur[8192 + boff];
      }
      #pragma unroll
      for (int m = 0; m < 4; ++m) {
        int rowA = wr * 64 + m * 16 + lr;
        int aoff = rowA * 64 + ((cc ^ (rowA & 7)) * 8);
        f16x8 av = *(const f16x8*)&cur[aoff];
        #pragma unroll
        for (int n = 0; n < 2; ++n)
          acc[m*2+n] = __builtin_amdgcn_mfma_f32_16x16x32_f16(av, bv[n], acc[m*2+n], 0, 0, 0);
      }
    }
    __syncthreads();
  }

  float rs = rsqrtf(sbuf[b]);
  float rv[2];
  #pragma unroll
  for (int n = 0; n < 2; ++n)
    rv[n] = rvec[(size_t)b*DD + f0 + wc*32 + n*16 + lr];
  float* ob = out + (size_t)b*TT*DD;
  #pragma unroll
  for (int m = 0; m < 4; ++m) {
    #pragma unroll
    for (int n = 0; n < 2; ++n) {
      int col = f0 + wc * 32 + n * 16 + lr;
      int row0 = t0 + wr * 64 + m * 16 + lg * 4;
      #pragma unroll
      for (int r = 0; r < 4; ++r)
        ob[(size_t)(row0 + r)*DD + col] = (acc[m*2+n][r] - rv[n]) * rs;
    }
  }
}

extern "C" void kernel_launch(void* const* d_in, const int* in_sizes, int n_in,
                              void* d_out, int out_size, void* d_ws, size_t ws_size,
                              hipStream_t stream) {
  const float* x     = (const float*)d_in[0];
  const float* gamma = (const float*)d_in[1];
  const float* beta  = (const float*)d_in[2];
  float* out = (float*)d_out;

  float* wsf  = (float*)d_ws;
  float* mu   = wsf;                       // 16384 f32
  float* sbuf = wsf + 16384;               // 64
  float* rvec = wsf + 16448;               // 16384
  unsigned short* nsb = (unsigned short*)(wsf + 32832);  // 16B aligned
  const size_t MATU = (size_t)BB * DD * DD;      // 4194304 ushorts (8 MB) per plane
  unsigned short* H[5];
  for (int k = 0; k < 5; ++k) H[k] = nsb + (size_t)k * MATU;
  unsigned short* A = nsb + 5 * MATU;      // 64*2048*256 ushorts = 67 MB
  float* part = (float*)H[1];              // 1 MB alias; dead before P0 writes H1

  prepass_kernel<<<dim3(16, BB), 256, 0, stream>>>(x, gamma, beta, A, part);
  mu_finalize_kernel<<<BB, 256, 0, stream>>>(part, gamma, beta, mu);
  cov_mfma<<<dim3(10, BB), 256, 0, stream>>>(A, mu, H[0]);
  power_kernel<<<BB, 256, 0, stream>>>(H[0], sbuf);

  // Tuned 3-stage NS: S1 (a=1,b=2) fused from C; S2, S3 vanilla (a=1/2,b=3)
  bgemm_p0<<<dim3(4, BB), 512, 0, stream>>>(H[0], H[3], H[1], sbuf);          // Y1->H3, Z1->H1
  bgemm_mfma2<<<dim3(4, BB), 512, 0, stream>>>(H[1], H[3], H[2], -1.f, 3.f);  // M2->H2
  bgemm_dual2<<<dim3(8, BB), 512, 0, stream>>>(H[3], H[2], H[0],              // Y2->H0
                                               H[2], H[1], H[4]);             // Z2->H4
  bgemm_mfma2<<<dim3(4, BB), 512, 0, stream>>>(H[4], H[0], H[2], -1.f, 3.f);  // M3->H2
  bgemm_mfma2<<<dim3(4, BB), 512, 0, stream>>>(H[2], H[4], H[1], 0.5f, 0.f);  // Z3->H1

  matvec_r<<<BB, 256, 0, stream>>>(mu, H[1], rvec);
  out_mfma2<<<dim3(32, BB), 512, 0, stream>>>(A, H[1], rvec, sbuf, out);
}

// Round 14
// 198.024 us; speedup vs baseline: 1.1122x; 1.0089x over previous
//
#include <hip/hip_runtime.h>
#include <cstddef>

#define TT 2048
#define BB 64
#define DD 256
#define LN_EPS 1e-5f
#define WEPS 1e-4f

typedef __attribute__((ext_vector_type(8))) short short8;
typedef __attribute__((ext_vector_type(4))) float f32x4;
typedef __attribute__((ext_vector_type(8))) _Float16 f16x8;
typedef __attribute__((ext_vector_type(4))) _Float16 f16x4;

__device__ __forceinline__ unsigned short f2h(float f) {
  _Float16 h = (_Float16)f;
  return *(unsigned short*)&h;
}
__device__ __forceinline__ float h2f(unsigned short u) {
  _Float16 h = *(_Float16*)&u;
  return (float)h;
}
__device__ __forceinline__ void gload16(unsigned short* lds, const unsigned short* g) {
  __builtin_amdgcn_global_load_lds(
      (const __attribute__((address_space(1))) void*)g,
      (__attribute__((address_space(3))) void*)lds, 16, 0, 0);
}

// ---- K1: LN stats + write A = LN(x) fp16 + column partial sums ----
__global__ __launch_bounds__(256) void prepass_kernel(const float* __restrict__ x,
    const float* __restrict__ gamma, const float* __restrict__ beta,
    unsigned short* __restrict__ A, float* __restrict__ part) {
  int c = blockIdx.x;
  int b = blockIdx.y;
  int tid = threadIdx.x;
  int wave = tid >> 6, lane = tid & 63;
  int rowbase = b * TT + c * 128 + wave * 32;
  const float* xb = x + (size_t)rowbase * DD + lane * 4;
  unsigned short* Ab = A + (size_t)rowbase * DD + lane * 4;
  float4 g4 = *(const float4*)&gamma[lane * 4];
  float4 b4 = *(const float4*)&beta[lane * 4];
  float a0 = 0.f, a1 = 0.f, a2 = 0.f, a3 = 0.f;
  for (int i = 0; i < 32; ++i) {
    float4 v = *(const float4*)&xb[(size_t)i * DD];
    float s  = v.x + v.y + v.z + v.w;
    float sq = v.x*v.x + v.y*v.y + v.z*v.z + v.w*v.w;
    #pragma unroll
    for (int off = 32; off; off >>= 1) { s += __shfl_xor(s, off); sq += __shfl_xor(sq, off); }
    float mean = s * (1.f/DD);
    float var  = fmaxf(sq * (1.f/DD) - mean*mean, 0.f);
    float rstd = rsqrtf(var + LN_EPS);
    float c0 = (v.x - mean) * rstd, c1 = (v.y - mean) * rstd;
    float c2 = (v.z - mean) * rstd, c3 = (v.w - mean) * rstd;
    a0 += c0; a1 += c1; a2 += c2; a3 += c3;
    ushort4 w;
    w.x = f2h(c0 * g4.x + b4.x);
    w.y = f2h(c1 * g4.y + b4.y);
    w.z = f2h(c2 * g4.z + b4.z);
    w.w = f2h(c3 * g4.w + b4.w);
    *(ushort4*)&Ab[(size_t)i * DD] = w;
  }
  int pidx = c * 4 + wave;
  *(float4*)&part[((size_t)pidx*BB + b)*DD + lane*4] = make_float4(a0, a1, a2, a3);
}

// ---- K3: cov = (Gram(A) - T mu mu^T)/(T-1) + eps I ; mu folded from part ----
__global__ __launch_bounds__(256) void cov_mfma(const unsigned short* __restrict__ A,
    const float* __restrict__ part, const float* __restrict__ gamma,
    const float* __restrict__ beta, unsigned short* __restrict__ Ch) {
  int flat = blockIdx.y * gridDim.x + blockIdx.x;  // [0,640)
  int kx = flat & 7, j = flat >> 3;
  int b = (kx << 3) + j / 10;
  int tile = j - (j / 10) * 10;
  int p = 0, t = tile;
  while (t >= 4 - p) { t -= (4 - p); ++p; }
  int q = p + t;
  int i0 = p * 64, j0 = q * 64;
  bool diag = (p == q);

  __shared__ unsigned short sm[16384];
  __shared__ float sMu[128];

  int tid = threadIdx.x;
  if (tid < 128) {
    int dg_ = (tid < 64) ? (i0 + tid) : (j0 + tid - 64);
    float s = 0.f;
    #pragma unroll 8
    for (int c = 0; c < 64; ++c) s += part[((size_t)c*BB + b)*DD + dg_];
    sMu[tid] = gamma[dg_] * s * (1.f/TT) + beta[dg_];
  }
  __syncthreads();

  int wave = tid >> 6, lane = tid & 63;
  int lr = lane & 15, lg = lane >> 4;
  int tg4 = tid >> 4;
  int dg  = tid & 15;
  int d0 = dg * 4;
  const unsigned short* Ab = A + (size_t)b*TT*DD;

  int ch16 = tg4 >> 1, half = tg4 & 1;
  int widx[4];
  #pragma unroll
  for (int jj = 0; jj < 4; ++jj) {
    int dl = d0 + jj;
    int swz = (ch16 ^ (dl & 7) ^ ((dl >> 3) & 7)) & 7;
    widx[jj] = dl*64 + swz*8 + half*4;
  }

  f32x4 acc[4] = {};

  #define COV_STAGE(k0v, dst)                                                  \
  {                                                                            \
    int trow = (k0v) + tg4 * 4;                                                \
    ushort4 sv0 = *(const ushort4*)&Ab[(size_t)(trow+0)*DD + i0 + d0];         \
    ushort4 sv1 = *(const ushort4*)&Ab[(size_t)(trow+1)*DD + i0 + d0];         \
    ushort4 sv2 = *(const ushort4*)&Ab[(size_t)(trow+2)*DD + i0 + d0];         \
    ushort4 sv3 = *(const ushort4*)&Ab[(size_t)(trow+3)*DD + i0 + d0];         \
    { ushort4 w = {sv0.x, sv1.x, sv2.x, sv3.x}; *(ushort4*)&(dst)[widx[0]] = w; } \
    { ushort4 w = {sv0.y, sv1.y, sv2.y, sv3.y}; *(ushort4*)&(dst)[widx[1]] = w; } \
    { ushort4 w = {sv0.z, sv1.z, sv2.z, sv3.z}; *(ushort4*)&(dst)[widx[2]] = w; } \
    { ushort4 w = {sv0.w, sv1.w, sv2.w, sv3.w}; *(ushort4*)&(dst)[widx[3]] = w; } \
    if (!diag) {                                                               \
      ushort4 t0v = *(const ushort4*)&Ab[(size_t)(trow+0)*DD + j0 + d0];       \
      ushort4 t1v = *(const ushort4*)&Ab[(size_t)(trow+1)*DD + j0 + d0];       \
      ushort4 t2v = *(const ushort4*)&Ab[(size_t)(trow+2)*DD + j0 + d0];       \
      ushort4 t3v = *(const ushort4*)&Ab[(size_t)(trow+3)*DD + j0 + d0];       \
      { ushort4 w = {t0v.x, t1v.x, t2v.x, t3v.x}; *(ushort4*)&(dst)[4096 + widx[0]] = w; } \
      { ushort4 w = {t0v.y, t1v.y, t2v.y, t3v.y}; *(ushort4*)&(dst)[4096 + widx[1]] = w; } \
      { ushort4 w = {t0v.z, t1v.z, t2v.z, t3v.z}; *(ushort4*)&(dst)[4096 + widx[2]] = w; } \
      { ushort4 w = {t0v.w, t1v.w, t2v.w, t3v.w}; *(ushort4*)&(dst)[4096 + widx[3]] = w; } \
    }                                                                          \
  }

  COV_STAGE(0, sm);
  __syncthreads();

  for (int kk = 0; kk < 32; ++kk) {
    unsigned short* cur = sm + (kk & 1) * 8192;
    if (kk < 31) {
      unsigned short* nxt = sm + ((kk & 1) ^ 1) * 8192;
      COV_STAGE((kk + 1) * 64, nxt);
    }
    const unsigned short* pA = cur;
    const unsigned short* pB = diag ? cur : (cur + 4096);
    #pragma unroll
    for (int ks = 0; ks < 2; ++ks) {
      int rowA = wave*16 + lr;
      int cc = ks*4 + lg;
      int aoff = rowA*64 + (((cc ^ (rowA&7) ^ ((rowA>>3)&7)) & 7) << 3);
      f16x8 av = *(const f16x8*)&pA[aoff];
      #pragma unroll
      for (int n = 0; n < 4; ++n) {
        int rowB = n*16 + lr;
        int boff = rowB*64 + (((cc ^ (rowB&7) ^ ((rowB>>3)&7)) & 7) << 3);
        f16x8 bv = *(const f16x8*)&pB[boff];
        acc[n] = __builtin_amdgcn_mfma_f32_16x16x32_f16(av, bv, acc[n], 0, 0, 0);
      }
    }
    __syncthreads();
  }
  #undef COV_STAGE

  float* sC = (float*)sm;
  #pragma unroll
  for (int n = 0; n < 4; ++n)
    #pragma unroll
    for (int r = 0; r < 4; ++r)
      sC[(wave*16 + lg*4 + r)*65 + n*16 + lr] = acc[n][r];
  __syncthreads();
  unsigned short* Chb = Ch + (size_t)b*DD*DD;
  const float invTm1 = 1.f / (float)(TT - 1);
  int row = tid >> 2, cb = (tid & 3) * 16;
  int gi = i0 + row;
  float mi = sMu[row] * (float)TT;
  unsigned short hv[16];
  #pragma unroll
  for (int e = 0; e < 16; ++e) {
    int gj = j0 + cb + e;
    float v = (sC[row*65 + cb + e] - mi * sMu[64 + cb + e]) * invTm1;
    if (gi == gj) v += WEPS;
    hv[e] = f2h(v);
    if (!diag) Chb[(size_t)gj*DD + gi] = hv[e];
  }
  size_t go = (size_t)gi*DD + j0 + cb;
  *(short8*)&Chb[go]     = *(short8*)&hv[0];
  *(short8*)&Chb[go + 8] = *(short8*)&hv[8];
}

// ---- K3b: power iteration (512 thr, 2/row) + mu materialization ----
__global__ __launch_bounds__(512) void power_kernel(
    const unsigned short* __restrict__ Ch, const float* __restrict__ part,
    const float* __restrict__ gamma, const float* __restrict__ beta,
    float* __restrict__ mu, float* __restrict__ sbuf) {
  int b = blockIdx.x, tid = threadIdx.x;
  __shared__ unsigned short sC[DD*DD];   // 128 KB
  __shared__ float v[DD];
  __shared__ float red[8];
  const unsigned short* Cb = Ch + (size_t)b*DD*DD;
  #pragma unroll
  for (int i = 0; i < 16; ++i) {
    int chunkid = i*512 + tid;
    int r = chunkid >> 5, ch = chunkid & 31;
    short8 qv = *(const short8*)&Cb[(size_t)chunkid*8];
    *(short8*)&sC[r*256 + ((ch ^ (r & 7)) << 3)] = qv;
  }
  if (tid < DD) {
    unsigned u = (unsigned)tid * 2654435761u;
    v[tid] = 0.5f + (float)((u >> 9) & 1023) * (1.f/1024.f);
    // mu materialization (for matvec_r later)
    float s = 0.f;
    #pragma unroll 8
    for (int c = 0; c < 64; ++c) s += part[((size_t)c*BB + b)*DD + tid];
    mu[(size_t)b*DD + tid] = gamma[tid] * s * (1.f/TT) + beta[tid];
  }
  __syncthreads();
  int row = tid >> 1, half = tid & 1;
  float lam = 1.f;
  for (int it = 0; it < 10; ++it) {
    float w = 0.f;
    #pragma unroll
    for (int i = 0; i < 16; ++i) {
      int ch = half * 16 + i;
      short8 hq = *(const short8*)&sC[row*256 + ((ch ^ (row & 7)) << 3)];
      const float* vp = &v[ch*8];
      #pragma unroll
      for (int e = 0; e < 8; ++e) w += h2f((unsigned short)hq[e]) * vp[e];
    }
    w += __shfl_xor(w, 1);
    float ssq = half ? 0.f : w * w;
    #pragma unroll
    for (int off = 32; off; off >>= 1) ssq += __shfl_xor(ssq, off);
    if ((tid & 63) == 0) red[tid >> 6] = ssq;
    __syncthreads();
    float nrm = sqrtf(red[0]+red[1]+red[2]+red[3]+red[4]+red[5]+red[6]+red[7]);
    lam = nrm;
    if (half == 0) v[row] = w / nrm;
    __syncthreads();
  }
  if (tid == 0) sbuf[b] = lam * 1.05f;
}

// ---- 128x128-tile fp16 MFMA GEMM body; symmetric-output mirror support ----
__device__ __forceinline__ void bgemm_tile2(
    const unsigned short* __restrict__ A, const unsigned short* __restrict__ B,
    unsigned short* __restrict__ Cc,
    float alpha, float diagBeta, int ti, int tj, int b, unsigned short* sm) {
  const int tid = threadIdx.x;
  const int i0g = ti * 128, j0g = tj * 128;
  const bool mirror = (ti != tj);
  const size_t mb = (size_t)b * DD * DD;
  const int wave = tid >> 6, lane = tid & 63;
  const int wr = wave >> 2, wc = wave & 3;
  const int lr = lane & 15, lg = lane >> 4;

  f32x4 acc[8] = {};

  #pragma unroll
  for (int p2 = 0; p2 < 2; ++p2) {
    int slot = tid + p2 * 512;
    int row = slot >> 3, c = slot & 7;
    int srcc = (c ^ (row & 7)) << 3;
    int base = (wave * 64 + p2 * 512) * 8;
    gload16(&sm[base], A + mb + (size_t)(i0g + row) * DD + srcc);
    gload16(&sm[8192 + base], B + mb + (size_t)(j0g + row) * DD + srcc);
  }
  __syncthreads();

  #pragma unroll
  for (int kk = 0; kk < 4; ++kk) {
    unsigned short* cur = sm + (kk & 1) * 16384;
    if (kk < 3) {
      unsigned short* nxt = sm + ((kk & 1) ^ 1) * 16384;
      int k0n = (kk + 1) * 64;
      #pragma unroll
      for (int p2 = 0; p2 < 2; ++p2) {
        int slot = tid + p2 * 512;
        int row = slot >> 3, c = slot & 7;
        int srcc = (c ^ (row & 7)) << 3;
        int base = (wave * 64 + p2 * 512) * 8;
        gload16(&nxt[base], A + mb + (size_t)(i0g + row) * DD + k0n + srcc);
        gload16(&nxt[8192 + base], B + mb + (size_t)(j0g + row) * DD + k0n + srcc);
      }
    }
    #pragma unroll
    for (int ks = 0; ks < 2; ++ks) {
      int cc = ks * 4 + lg;
      f16x8 bv[2];
      #pragma unroll
      for (int n = 0; n < 2; ++n) {
        int rowB = wc * 32 + n * 16 + lr;
        int boff = rowB * 64 + ((cc ^ (rowB & 7)) * 8);
        bv[n] = *(const f16x8*)&cur[8192 + boff];
      }
      #pragma unroll
      for (int m = 0; m < 4; ++m) {
        int rowA = wr * 64 + m * 16 + lr;
        int aoff = rowA * 64 + ((cc ^ (rowA & 7)) * 8);
        f16x8 av = *(const f16x8*)&cur[aoff];
        #pragma unroll
        for (int n = 0; n < 2; ++n)
          acc[m*2+n] = __builtin_amdgcn_mfma_f32_16x16x32_f16(av, bv[n], acc[m*2+n], 0, 0, 0);
      }
    }
    __syncthreads();
  }

  unsigned short hvv[4][2][4];
  #pragma unroll
  for (int m = 0; m < 4; ++m) {
    #pragma unroll
    for (int n = 0; n < 2; ++n) {
      int col = j0g + wc * 32 + n * 16 + lr;
      int row0 = i0g + wr * 64 + m * 16 + lg * 4;
      #pragma unroll
      for (int r = 0; r < 4; ++r) {
        float vv = alpha * acc[m*2+n][r];
        int row = row0 + r;
        if (row == col) vv += diagBeta;
        unsigned short h = f2h(vv);
        hvv[m][n][r] = h;
        Cc[mb + (size_t)row * DD + col] = h;
      }
    }
  }

  if (mirror) {
    // stash transposed into sm (free after k-loop) with XOR swizzle
    #pragma unroll
    for (int m = 0; m < 4; ++m)
      #pragma unroll
      for (int n = 0; n < 2; ++n) {
        int lcol = wc * 32 + n * 16 + lr;
        int lrow0 = wr * 64 + m * 16 + lg * 4;
        #pragma unroll
        for (int r = 0; r < 4; ++r)
          sm[lcol * 128 + ((lrow0 + r) ^ ((lcol & 7) << 3))] = hvv[m][n][r];
      }
    __syncthreads();
    #pragma unroll
    for (int ci = 0; ci < 4; ++ci) {
      int chunk = tid + ci * 512;          // 0..2047
      int mr = chunk >> 4, mc0 = (chunk & 15) * 8;
      f16x8 v = *(const f16x8*)&sm[mr * 128 + (mc0 ^ ((mr & 7) << 3))];
      *(f16x8*)&Cc[mb + (size_t)(j0g + mr) * DD + i0g + mc0] = v;
    }
    __syncthreads();
  }
}

// ut in {0,1,2} -> (ti,tj) in {(0,0),(0,1),(1,1)}
__global__ __launch_bounds__(512) void bgemm_mfma2(
    const unsigned short* __restrict__ A, const unsigned short* __restrict__ B,
    unsigned short* __restrict__ C, float alpha, float diagBeta) {
  __shared__ unsigned short sm[32768];
  int flat = blockIdx.x;                 // [0,192)
  int kx = flat & 7, j = flat >> 3;      // j in [0,24)
  int b = (kx << 3) + j / 3;
  int ut = j - (j / 3) * 3;
  bgemm_tile2(A, B, C, alpha, diagBeta, ut >> 1, (ut + 1) >> 1, b, sm);
}

__global__ __launch_bounds__(512) void bgemm_dual2(
    const unsigned short* __restrict__ A0, const unsigned short* __restrict__ B0,
    unsigned short* __restrict__ C0,
    const unsigned short* __restrict__ A1, const unsigned short* __restrict__ B1,
    unsigned short* __restrict__ C1) {
  __shared__ unsigned short sm[32768];
  int flat = blockIdx.x;                 // [0,384)
  int kx = flat & 7, j = flat >> 3;      // j in [0,48)
  int b = (kx << 3) + j / 6;
  int t6 = j - (j / 6) * 6;
  int half = t6 >= 3 ? 1 : 0;
  int ut = t6 - half * 3;
  if (half == 0)
    bgemm_tile2(A0, B0, C0, 0.5f, 0.f, ut >> 1, (ut + 1) >> 1, b, sm);
  else
    bgemm_tile2(A1, B1, C1, 0.5f, 0.f, ut >> 1, (ut + 1) >> 1, b, sm);
}

// ---- P0: tuned stage-1 (a=1,b=2): Y1 = 2C~ - C~^2 ; Z1 = 2I - C~ ; mirrored ----
__global__ __launch_bounds__(512) void bgemm_p0(
    const unsigned short* __restrict__ C, unsigned short* __restrict__ Y1,
    unsigned short* __restrict__ Z1, const float* __restrict__ sbuf) {
  __shared__ unsigned short sm[32768];
  int flat = blockIdx.x;                 // [0,192)
  int kx = flat & 7, j = flat >> 3;
  int b = (kx << 3) + j / 3;
  int ut = j - (j / 3) * 3;
  int ti = ut >> 1, tj = (ut + 1) >> 1;
  bool mirror = (ti != tj);

  const int tid = threadIdx.x;
  const int i0g = ti * 128, j0g = tj * 128;
  const size_t mb = (size_t)b * DD * DD;
  const int wave = tid >> 6, lane = tid & 63;
  const int wr = wave >> 2, wc = wave & 3;
  const int lr = lane & 15, lg = lane >> 4;

  f32x4 acc[8] = {};

  #pragma unroll
  for (int p2 = 0; p2 < 2; ++p2) {
    int slot = tid + p2 * 512;
    int row = slot >> 3, c = slot & 7;
    int srcc = (c ^ (row & 7)) << 3;
    int base = (wave * 64 + p2 * 512) * 8;
    gload16(&sm[base], C + mb + (size_t)(i0g + row) * DD + srcc);
    gload16(&sm[8192 + base], C + mb + (size_t)(j0g + row) * DD + srcc);
  }
  __syncthreads();

  #pragma unroll
  for (int kk = 0; kk < 4; ++kk) {
    unsigned short* cur = sm + (kk & 1) * 16384;
    if (kk < 3) {
      unsigned short* nxt = sm + ((kk & 1) ^ 1) * 16384;
      int k0n = (kk + 1) * 64;
      #pragma unroll
      for (int p2 = 0; p2 < 2; ++p2) {
        int slot = tid + p2 * 512;
        int row = slot >> 3, c = slot & 7;
        int srcc = (c ^ (row & 7)) << 3;
        int base = (wave * 64 + p2 * 512) * 8;
        gload16(&nxt[base], C + mb + (size_t)(i0g + row) * DD + k0n + srcc);
        gload16(&nxt[8192 + base], C + mb + (size_t)(j0g + row) * DD + k0n + srcc);
      }
    }
    #pragma unroll
    for (int ks = 0; ks < 2; ++ks) {
      int cc = ks * 4 + lg;
      f16x8 bv[2];
      #pragma unroll
      for (int n = 0; n < 2; ++n) {
        int rowB = wc * 32 + n * 16 + lr;
        int boff = rowB * 64 + ((cc ^ (rowB & 7)) * 8);
        bv[n] = *(const f16x8*)&cur[8192 + boff];
      }
      #pragma unroll
      for (int m = 0; m < 4; ++m) {
        int rowA = wr * 64 + m * 16 + lr;
        int aoff = rowA * 64 + ((cc ^ (rowA & 7)) * 8);
        f16x8 av = *(const f16x8*)&cur[aoff];
        #pragma unroll
        for (int n = 0; n < 2; ++n)
          acc[m*2+n] = __builtin_amdgcn_mfma_f32_16x16x32_f16(av, bv[n], acc[m*2+n], 0, 0, 0);
      }
    }
    __syncthreads();
  }

  float invs = 1.f / sbuf[b];
  float a2 = -invs * invs;
  float a1c = 2.f * invs;
  float z1c = -invs;
  unsigned short yvv[4][2][4], zvv[4][2][4];
  #pragma unroll
  for (int m = 0; m < 4; ++m) {
    #pragma unroll
    for (int n = 0; n < 2; ++n) {
      int col = j0g + wc * 32 + n * 16 + lr;
      int row0 = i0g + wr * 64 + m * 16 + lg * 4;
      #pragma unroll
      for (int r = 0; r < 4; ++r) {
        int row = row0 + r;
        float cv = h2f(C[mb + (size_t)row * DD + col]);
        float yv = a2 * acc[m*2+n][r] + a1c * cv;
        float zv = z1c * cv + ((row == col) ? 2.f : 0.f);
        unsigned short yh = f2h(yv), zh = f2h(zv);
        yvv[m][n][r] = yh; zvv[m][n][r] = zh;
        Y1[mb + (size_t)row * DD + col] = yh;
        Z1[mb + (size_t)row * DD + col] = zh;
      }
    }
  }
  if (mirror) {
    #pragma unroll
    for (int m = 0; m < 4; ++m)
      #pragma unroll
      for (int n = 0; n < 2; ++n) {
        int lcol = wc * 32 + n * 16 + lr;
        int lrow0 = wr * 64 + m * 16 + lg * 4;
        #pragma unroll
        for (int r = 0; r < 4; ++r) {
          int idx = lcol * 128 + ((lrow0 + r) ^ ((lcol & 7) << 3));
          sm[idx] = yvv[m][n][r];
          sm[16384 + idx] = zvv[m][n][r];
        }
      }
    __syncthreads();
    #pragma unroll
    for (int ci = 0; ci < 4; ++ci) {
      int chunk = tid + ci * 512;
      int mr = chunk >> 4, mc0 = (chunk & 15) * 8;
      int idx = mr * 128 + (mc0 ^ ((mr & 7) << 3));
      f16x8 vy = *(const f16x8*)&sm[idx];
      f16x8 vz = *(const f16x8*)&sm[16384 + idx];
      size_t go = mb + (size_t)(j0g + mr) * DD + i0g + mc0;
      *(f16x8*)&Y1[go] = vy;
      *(f16x8*)&Z1[go] = vz;
    }
  }
}

// ---- rvec = mu^T W ----
__global__ __launch_bounds__(256) void matvec_r(const float* __restrict__ mu,
    const unsigned short* __restrict__ W, float* __restrict__ rvec) {
  int b = blockIdx.x, f = threadIdx.x;
  __shared__ float sMu[DD];
  sMu[f] = mu[(size_t)b*DD + f];
  __syncthreads();
  const unsigned short* Wb = W + (size_t)b*DD*DD;
  float acc = 0.f;
  #pragma unroll 8
  for (int d = 0; d < DD; ++d) acc += sMu[d] * h2f(Wb[(size_t)d*DD + f]);
  rvec[(size_t)b*DD + f] = acc;
}

// ---- K6: out = (A W - 1 rvec^T)/sqrt(s); pure dual-gload GEMM, NT stores ----
__global__ __launch_bounds__(512) void out_mfma2(const unsigned short* __restrict__ A,
    const unsigned short* __restrict__ W, const float* __restrict__ rvec,
    const float* __restrict__ sbuf, float* __restrict__ out) {
  int flat = blockIdx.y * gridDim.x + blockIdx.x;  // [0,2048)
  int kx = flat & 7, j = flat >> 3;
  int b = (kx << 3) + (j >> 5);
  int tile = j & 31;
  int t0 = (tile >> 1) * 128, f0 = (tile & 1) * 128;
  __shared__ unsigned short sm[32768];

  int tid = threadIdx.x;
  const int wave = tid >> 6, lane = tid & 63;
  const int wr = wave >> 2, wc = wave & 3;
  const int lr = lane & 15, lg = lane >> 4;
  const unsigned short* Ab = A + (size_t)b*TT*DD;
  const unsigned short* Wb = W + (size_t)b*DD*DD;

  f32x4 acc[8] = {};

  #pragma unroll
  for (int p2 = 0; p2 < 2; ++p2) {
    int slot = tid + p2 * 512;
    int row = slot >> 3, c = slot & 7;
    int srcc = (c ^ (row & 7)) << 3;
    int base = (wave * 64 + p2 * 512) * 8;
    gload16(&sm[base], Ab + (size_t)(t0 + row) * DD + srcc);
    gload16(&sm[8192 + base], Wb + (size_t)(f0 + row) * DD + srcc);
  }
  __syncthreads();

  #pragma unroll
  for (int kk = 0; kk < 4; ++kk) {
    unsigned short* cur = sm + (kk & 1) * 16384;
    if (kk < 3) {
      unsigned short* nxt = sm + ((kk & 1) ^ 1) * 16384;
      int k0n = (kk + 1) * 64;
      #pragma unroll
      for (int p2 = 0; p2 < 2; ++p2) {
        int slot = tid + p2 * 512;
        int row = slot >> 3, c = slot & 7;
        int srcc = (c ^ (row & 7)) << 3;
        int base = (wave * 64 + p2 * 512) * 8;
        gload16(&nxt[base], Ab + (size_t)(t0 + row) * DD + k0n + srcc);
        gload16(&nxt[8192 + base], Wb + (size_t)(f0 + row) * DD + k0n + srcc);
      }
    }
    #pragma unroll
    for (int ks = 0; ks < 2; ++ks) {
      int cc = ks * 4 + lg;
      f16x8 bv[2];
      #pragma unroll
      for (int n = 0; n < 2; ++n) {
        int rowB = wc * 32 + n * 16 + lr;
        int boff = rowB * 64 + ((cc ^ (rowB & 7)) * 8);
        bv[n] = *(const f16x8*)&cur[8192 + boff];
      }
      #pragma unroll
      for (int m = 0; m < 4; ++m) {
        int rowA = wr * 64 + m * 16 + lr;
        int aoff = rowA * 64 + ((cc ^ (rowA & 7)) * 8);
        f16x8 av = *(const f16x8*)&cur[aoff];
        #pragma unroll
        for (int n = 0; n < 2; ++n)
          acc[m*2+n] = __builtin_amdgcn_mfma_f32_16x16x32_f16(av, bv[n], acc[m*2+n], 0, 0, 0);
      }
    }
    __syncthreads();
  }

  float rs = rsqrtf(sbuf[b]);
  float rv[2];
  #pragma unroll
  for (int n = 0; n < 2; ++n)
    rv[n] = rvec[(size_t)b*DD + f0 + wc*32 + n*16 + lr];
  float* ob = out + (size_t)b*TT*DD;
  #pragma unroll
  for (int m = 0; m < 4; ++m) {
    #pragma unroll
    for (int n = 0; n < 2; ++n) {
      int col = f0 + wc * 32 + n * 16 + lr;
      int row0 = t0 + wr * 64 + m * 16 + lg * 4;
      #pragma unroll
      for (int r = 0; r < 4; ++r)
        __builtin_nontemporal_store((acc[m*2+n][r] - rv[n]) * rs,
                                    &ob[(size_t)(row0 + r)*DD + col]);
    }
  }
}

extern "C" void kernel_launch(void* const* d_in, const int* in_sizes, int n_in,
                              void* d_out, int out_size, void* d_ws, size_t ws_size,
                              hipStream_t stream) {
  const float* x     = (const float*)d_in[0];
  const float* gamma = (const float*)d_in[1];
  const float* beta  = (const float*)d_in[2];
  float* out = (float*)d_out;

  float* wsf  = (float*)d_ws;
  float* mu   = wsf;                       // 16384 f32
  float* sbuf = wsf + 16384;               // 64
  float* rvec = wsf + 16448;               // 16384
  unsigned short* nsb = (unsigned short*)(wsf + 32832);
  const size_t MATU = (size_t)BB * DD * DD;      // 8 MB/plane
  unsigned short* H[5];
  for (int k = 0; k < 5; ++k) H[k] = nsb + (size_t)k * MATU;
  unsigned short* A = nsb + 5 * MATU;      // 64 MB
  // part (4 MB) aliased onto H3: read by cov+power (before P0 writes H3)
  float* part = (float*)H[3];

  prepass_kernel<<<dim3(16, BB), 256, 0, stream>>>(x, gamma, beta, A, part);
  cov_mfma<<<dim3(10, BB), 256, 0, stream>>>(A, part, gamma, beta, H[0]);
  power_kernel<<<BB, 512, 0, stream>>>(H[0], part, gamma, beta, mu, sbuf);

  // Tuned 3-stage NS, symmetric 3-tile GEMMs with mirror
  bgemm_p0<<<dim3(192), 512, 0, stream>>>(H[0], H[3], H[1], sbuf);            // Y1->H3, Z1->H1
  bgemm_mfma2<<<dim3(192), 512, 0, stream>>>(H[1], H[3], H[2], -1.f, 3.f);    // M2->H2
  bgemm_dual2<<<dim3(384), 512, 0, stream>>>(H[3], H[2], H[0],                // Y2->H0
                                             H[2], H[1], H[4]);               // Z2->H4
  bgemm_mfma2<<<dim3(192), 512, 0, stream>>>(H[4], H[0], H[2], -1.f, 3.f);    // M3->H2
  bgemm_mfma2<<<dim3(192), 512, 0, stream>>>(H[2], H[4], H[1], 0.5f, 0.f);    // Z3->H1

  matvec_r<<<BB, 256, 0, stream>>>(mu, H[1], rvec);
  out_mfma2<<<dim3(32, BB), 512, 0, stream>>>(A, H[1], rvec, sbuf, out);
}